// Round 9
// baseline (295.266 us; speedup 1.0000x reference)
//
#include <hip/hip_runtime.h>
#include <hip/hip_bf16.h>

// Causal attention head. B=8, T=4096, D_EMBED=128, HEAD=64. f32 wire, bf16 MFMA.
typedef __attribute__((ext_vector_type(8))) short bf16x8;
typedef __attribute__((ext_vector_type(4))) short short4v;
typedef __attribute__((ext_vector_type(4))) float f32x4;

#define MFMA16(a, b, c) __builtin_amdgcn_mfma_f32_16x16x32_bf16((a), (b), (c), 0, 0, 0)

// K=16 MFMA: P's S^T C-layout == its A-frag layout -> PV straight from registers.
#if __has_builtin(__builtin_amdgcn_mfma_f32_16x16x16bf16_1k)
#define HAVE_X16 1
#define MFMAX16(a, b, c) __builtin_amdgcn_mfma_f32_16x16x16bf16_1k((a), (b), (c), 0, 0, 0)
#elif __has_builtin(__builtin_amdgcn_mfma_f32_16x16x16_bf16)
#define HAVE_X16 1
#define MFMAX16(a, b, c) __builtin_amdgcn_mfma_f32_16x16x16_bf16((a), (b), (c), 0, 0, 0)
#else
#define HAVE_X16 0
#endif

constexpr int Bn = 8, Tn = 4096, Dn = 128, Hn = 64;

__device__ inline unsigned short f2b(float f) {
    union { float f; unsigned u; } v; v.f = f;
    unsigned r = v.u + 0x7fff + ((v.u >> 16) & 1);   // RNE, inputs finite
    return (unsigned short)(r >> 16);
}
__device__ inline float b2f(unsigned short u) {
    union { unsigned u; float f; } v; v.u = ((unsigned)u) << 16;
    return v.f;
}
#if __has_builtin(__builtin_amdgcn_cvt_pk_bf16_f32)
typedef __attribute__((ext_vector_type(2))) __bf16 bf16x2_t;
__device__ inline unsigned pk2(float a, float b) {
    union { bf16x2_t v; unsigned u; } c;
    c.v = __builtin_amdgcn_cvt_pk_bf16_f32(a, b);
    return c.u;
}
#else
__device__ inline unsigned pk2(float a, float b) {
    return (unsigned)f2b(a) | ((unsigned)f2b(b) << 16);
}
#endif
__device__ inline short4v pk4(float a, float b, float c, float d) {
    union { unsigned u[2]; short4v s; } r;
    r.u[0] = pk2(a, b); r.u[1] = pk2(c, d);
    return r.s;
}

// ---- Kernel 0: transpose weights to bf16 WT[3][64][128]; zero split-k counters ----
__global__ void wtrans(const float* __restrict__ Wq,
                       const float* __restrict__ Wk,
                       const float* __restrict__ Wv,
                       unsigned short* __restrict__ WT,
                       int* __restrict__ cnt) {
    int g = blockIdx.x * 256 + threadIdx.x;
    if (g < 512) cnt[g] = 0;
    int m = blockIdx.x;
    const float* W = (m == 0) ? Wq : (m == 1) ? Wk : Wv;
    unsigned short* o = WT + m * Hn * Dn;
    for (int i = threadIdx.x; i < Hn * Dn; i += blockDim.x) {
        int n = i >> 7, k = i & 127;
        o[i] = f2b(W[k * Hn + n]);
    }
}

// ---- Kernel 1: QKV projection, coalesced I/O via LDS tiles. ----
__global__ __launch_bounds__(256) void qkv(const float* __restrict__ X,
                                           const unsigned short* __restrict__ WT,
                                           unsigned short* __restrict__ Qp,
                                           unsigned short* __restrict__ Kp,
                                           unsigned short* __restrict__ VTp) {
    __shared__ unsigned short xt[64 * 136];
    __shared__ unsigned short ot[64 * 72];
    int tid = threadIdx.x, w = tid >> 6, lane = tid & 63, quad = lane >> 4, l15 = lane & 15;
    int m0 = blockIdx.x * 64;
    int b = m0 >> 12, tloc = m0 & (Tn - 1);
    const float kLog2Scale = 0.12751879523175464f;  // (1/sqrt(128)) * log2(e)

    #pragma unroll
    for (int c = 0; c < 8; c++) {
        int e = tid * 4 + c * 1024;
        int row = e >> 7, col = e & 127;
        f32x4 v = *(const f32x4*)&X[(size_t)(m0 + row) * Dn + col];
        *(short4v*)&xt[row * 136 + col] = pk4(v[0], v[1], v[2], v[3]);
    }
    __syncthreads();

    bf16x8 a[4];
    #pragma unroll
    for (int kt = 0; kt < 4; kt++)
        a[kt] = *(const bf16x8*)&xt[(w * 16 + l15) * 136 + kt * 32 + quad * 8];

    for (int mat = 0; mat < 3; mat++) {
        f32x4 acc[4];
        #pragma unroll
        for (int nt = 0; nt < 4; nt++) {
            acc[nt] = (f32x4){0.f, 0.f, 0.f, 0.f};
            const unsigned short* wtm = WT + mat * Hn * Dn + (size_t)(nt * 16 + l15) * Dn + quad * 8;
            #pragma unroll
            for (int kt = 0; kt < 4; kt++)
                acc[nt] = MFMA16(a[kt], *(const bf16x8*)&wtm[kt * 32], acc[nt]);
        }
        __syncthreads();
        if (mat < 2) {
            float sc = (mat == 0) ? kLog2Scale : 1.0f;   // fold softmax scale into Q
            #pragma unroll
            for (int nt = 0; nt < 4; nt++)
                #pragma unroll
                for (int rg = 0; rg < 4; rg++)
                    ot[(w * 16 + quad * 4 + rg) * 72 + nt * 16 + l15] = f2b(acc[nt][rg] * sc);
        } else {
            #pragma unroll
            for (int nt = 0; nt < 4; nt++)
                *(short4v*)&ot[(nt * 16 + l15) * 72 + w * 16 + quad * 4] =
                    pk4(acc[nt][0], acc[nt][1], acc[nt][2], acc[nt][3]);
        }
        __syncthreads();
        if (mat < 2) {
            unsigned short* O = mat ? Kp : Qp;
            #pragma unroll
            for (int i = 0; i < 2; i++) {
                int row = (tid >> 3) + 32 * i, ch = tid & 7;
                *(bf16x8*)&O[(size_t)(m0 + row) * Hn + ch * 8] = *(const bf16x8*)&ot[row * 72 + ch * 8];
            }
        } else {
            #pragma unroll
            for (int i = 0; i < 2; i++) {
                int h = (tid >> 3) + 32 * i, ch = tid & 7;
                *(bf16x8*)&VTp[((size_t)(b * Hn + h)) * Tn + tloc + ch * 8] = *(const bf16x8*)&ot[h * 72 + ch * 8];
            }
        }
    }
}

// ---- Kernel 2: balanced flash attention + fused last-block split-k combine. ----
__global__ __launch_bounds__(256) void attn(const unsigned short* __restrict__ Qp,
                                            const unsigned short* __restrict__ Kp,
                                            const unsigned short* __restrict__ VTp,
                                            float* __restrict__ Out,
                                            unsigned short* __restrict__ Part,
                                            float* __restrict__ Lpart,
                                            int* __restrict__ cnt) {
    __shared__ __align__(16) char shmem[18432];      // Ks+Vs, reused as Cbuf in epilogue
    unsigned short* Ks = (unsigned short*)shmem;     // [64][72]
    unsigned short* Vs = Ks + 64 * 72;               // [64][72]
#if !HAVE_X16
    __shared__ __align__(16) unsigned short Ps[4][32 * 40];
#endif
    __shared__ float Lbuf[2][64];
    __shared__ int lastflag;

    int idx = blockIdx.x;
    int b = idx & 7;
    int c = 159 - (idx >> 3);
    int qt, ch, nch;
    if (c < 16)      { qt = c;                 ch = 0;          nch = 1; }
    else if (c < 48) { int t = c - 16; qt = 16 + (t >> 1); ch = t & 1;      nch = 2; }
    else if (c < 96) { int t = c - 48; int q3 = t / 3; qt = 32 + q3; ch = t - 3 * q3; nch = 3; }
    else             { int t = c - 96; qt = 48 + (t >> 2); ch = t & 3;      nch = 4; }
    int k0 = ch * 16, k1 = min(qt, k0 + 15);

    int tid = threadIdx.x, w = tid >> 6, lane = tid & 63, quad = lane >> 4, l15 = lane & 15;
    int qh = w & 1, kh = w >> 1;
    int Q0 = qt * 64;
    const unsigned short* Kb = Kp + (size_t)b * Tn * Hn;
    const unsigned short* Vb = VTp + (size_t)b * Hn * Tn;

    int srow = tid >> 3, scol = (tid & 7) * 8;       // staging: 2 f32x4/thread/tile
    const f32x4* Ksrc = (const f32x4*)Kb;

    f32x4 kr[2], vr[2];
    #pragma unroll
    for (int i = 0; i < 2; i++) kr[i] = Ksrc[k0 * 512 + tid + i * 256];
    #pragma unroll
    for (int i = 0; i < 2; i++) vr[i] = *(const f32x4*)&Vb[(size_t)(srow + i * 32) * Tn + k0 * 64 + scol];

    bf16x8 qf[2][2];
    {
        const unsigned short* Qb = Qp + ((size_t)b * Tn + Q0 + qh * 32) * Hn;
        #pragma unroll
        for (int nq = 0; nq < 2; nq++)
            #pragma unroll
            for (int hc = 0; hc < 2; hc++)
                qf[nq][hc] = *(const bf16x8*)&Qb[(nq * 16 + l15) * Hn + hc * 32 + quad * 8];
    }

    f32x4 o[2][4];
    #pragma unroll
    for (int nq = 0; nq < 2; nq++)
        #pragma unroll
        for (int nh = 0; nh < 4; nh++) o[nq][nh] = (f32x4){0.f, 0.f, 0.f, 0.f};
    float li[2] = {0.f, 0.f};

    for (int kt = k0; kt <= k1; kt++) {
        __syncthreads();
        #pragma unroll
        for (int i = 0; i < 2; i++) *(f32x4*)&Ks[(srow + i * 32) * 72 + scol] = kr[i];
        #pragma unroll
        for (int i = 0; i < 2; i++) *(f32x4*)&Vs[(srow + i * 32) * 72 + scol] = vr[i];
        __syncthreads();
        if (kt < k1) {   // prefetch next tile; latency overlaps compute
            #pragma unroll
            for (int i = 0; i < 2; i++) kr[i] = Ksrc[(kt + 1) * 512 + tid + i * 256];
            #pragma unroll
            for (int i = 0; i < 2; i++)
                vr[i] = *(const f32x4*)&Vb[(size_t)(srow + i * 32) * Tn + (kt + 1) * 64 + scol];
        }

        bf16x8 kf[2][2];
        #pragma unroll
        for (int mt = 0; mt < 2; mt++)
            #pragma unroll
            for (int hc = 0; hc < 2; hc++)
                kf[mt][hc] = *(const bf16x8*)&Ks[(kh * 32 + mt * 16 + l15) * 72 + hc * 32 + quad * 8];

        // S^T tiles: rows k' = mt*16+quad*4+rg, cols q = nq*16+l15 (log2-scaled)
        f32x4 s[2][2];
        #pragma unroll
        for (int mt = 0; mt < 2; mt++)
            #pragma unroll
            for (int nq = 0; nq < 2; nq++) {
                f32x4 acc = {0.f, 0.f, 0.f, 0.f};
                acc = MFMA16(kf[mt][0], qf[nq][0], acc);
                acc = MFMA16(kf[mt][1], qf[nq][1], acc);
                s[mt][nq] = acc;
            }

        bool diag = (kt == qt);
        int kbase = kt * 64 + kh * 32 + quad * 4;
        int qbase = Q0 + qh * 32 + l15;

#if HAVE_X16
        // V B-frags for K=16: B[k=quad*4+j][n=l15->h], from Vs[h][k'] rows (b64)
        short4v vB[2][4];
        #pragma unroll
        for (int mt = 0; mt < 2; mt++)
            #pragma unroll
            for (int nh = 0; nh < 4; nh++)
                vB[mt][nh] = *(const short4v*)&Vs[(nh * 16 + l15) * 72 + kh * 32 + mt * 16 + quad * 4];
        short4v pkv[2][2];
        #pragma unroll
        for (int mt = 0; mt < 2; mt++) {
            #pragma unroll
            for (int nq = 0; nq < 2; nq++) {
                float p[4];
                #pragma unroll
                for (int rg = 0; rg < 4; rg++) {
                    float pe = __builtin_amdgcn_exp2f(s[mt][nq][rg]);
                    if (diag && (kbase + mt * 16 + rg > qbase + nq * 16)) pe = 0.f;
                    li[nq] += pe;
                    p[rg] = pe;
                }
                pkv[mt][nq] = pk4(p[0], p[1], p[2], p[3]);
            }
        }
        // PV: o[q][h] += P(A) x V(B); P A-frag IS the S^T C-layout -> no transform
        #pragma unroll
        for (int mt = 0; mt < 2; mt++)
            #pragma unroll
            for (int nq = 0; nq < 2; nq++)
                #pragma unroll
                for (int nh = 0; nh < 4; nh++)
                    o[nq][nh] = MFMAX16(pkv[mt][nq], vB[mt][nh], o[nq][nh]);
#else
        bf16x8 vf[4];
        #pragma unroll
        for (int nh = 0; nh < 4; nh++)
            vf[nh] = *(const bf16x8*)&Vs[(nh * 16 + l15) * 72 + kh * 32 + quad * 8];
        unsigned short* Pw = &Ps[w][0];
        #pragma unroll
        for (int mt = 0; mt < 2; mt++) {
            #pragma unroll
            for (int nq = 0; nq < 2; nq++) {
                float p[4];
                #pragma unroll
                for (int rg = 0; rg < 4; rg++) {
                    float pe = __builtin_amdgcn_exp2f(s[mt][nq][rg]);
                    if (diag && (kbase + mt * 16 + rg > qbase + nq * 16)) pe = 0.f;
                    li[nq] += pe;
                    p[rg] = pe;
                }
                *(short4v*)&Pw[(nq * 16 + l15) * 40 + mt * 16 + quad * 4] = pk4(p[0], p[1], p[2], p[3]);
            }
        }
        bf16x8 pf[2];
        #pragma unroll
        for (int nq = 0; nq < 2; nq++)
            pf[nq] = *(const bf16x8*)&Pw[(nq * 16 + l15) * 40 + quad * 8];
        #pragma unroll
        for (int nq = 0; nq < 2; nq++)
            #pragma unroll
            for (int nh = 0; nh < 4; nh++)
                o[nq][nh] = MFMA16(pf[nq], vf[nh], o[nq][nh]);
#endif
    }

    // ---- epilogue: combine kh halves; write partial or final ----
    __syncthreads();                                  // loop LDS reads done; reuse shmem
    float (*Cbuf)[32][66] = (float (*)[32][66])shmem; // [2][32][66] = 16896 B
    #pragma unroll
    for (int nq = 0; nq < 2; nq++) {
        li[nq] += __shfl_xor(li[nq], 16);
        li[nq] += __shfl_xor(li[nq], 32);
    }
    if (lane < 16) {
        Lbuf[kh][qh * 32 + lane]      = li[0];
        Lbuf[kh][qh * 32 + 16 + lane] = li[1];
    }
    if (kh == 1) {
        #pragma unroll
        for (int nq = 0; nq < 2; nq++)
            #pragma unroll
            for (int nh = 0; nh < 4; nh++)
                #pragma unroll
                for (int rg = 0; rg < 4; rg++)
                    Cbuf[qh][nq * 16 + quad * 4 + rg][nh * 16 + l15] = o[nq][nh][rg];
    }
    __syncthreads();
    if (kh == 0) {
        #pragma unroll
        for (int nq = 0; nq < 2; nq++) {
            #pragma unroll
            for (int rg = 0; rg < 4; rg++) {
                int qloc = nq * 16 + quad * 4 + rg;
                size_t row = (size_t)b * Tn + Q0 + qh * 32 + qloc;
                if (nch == 1) {
                    float inv = 1.0f / (Lbuf[0][qh * 32 + qloc] + Lbuf[1][qh * 32 + qloc]);
                    #pragma unroll
                    for (int nh = 0; nh < 4; nh++)
                        Out[row * Hn + nh * 16 + l15] =
                            (o[nq][nh][rg] + Cbuf[qh][qloc][nh * 16 + l15]) * inv;
                } else if (ch == 0) {   // raw f32 partial into Out
                    #pragma unroll
                    for (int nh = 0; nh < 4; nh++)
                        Out[row * Hn + nh * 16 + l15] =
                            o[nq][nh][rg] + Cbuf[qh][qloc][nh * 16 + l15];
                } else {                // bf16 partial into ws
                    size_t pb = (((size_t)b * 64 + qt) * 3 + (ch - 1)) * 4096;
                    #pragma unroll
                    for (int nh = 0; nh < 4; nh++)
                        Part[pb + (qh * 32 + qloc) * 64 + nh * 16 + l15] =
                            f2b(o[nq][nh][rg] + Cbuf[qh][qloc][nh * 16 + l15]);
                }
            }
        }
    }
    if (nch > 1) {
        if (tid < 64)
            Lpart[(((size_t)b * 64 + qt) * 4 + ch) * 64 + tid] = Lbuf[0][tid] + Lbuf[1][tid];
        __threadfence();     // release this block's partial writes (device scope)
        __syncthreads();
        if (tid == 0) lastflag = (atomicAdd(&cnt[b * 64 + qt], 1) == nch - 1);
        __syncthreads();
        if (lastflag) {      // last chunk combines (overlaps other blocks' compute)
            __threadfence(); // acquire
            const float* Lp = &Lpart[((size_t)b * 64 + qt) * 256];
            size_t gbase = ((size_t)b * Tn + qt * 64) * Hn;
            #pragma unroll
            for (int i = 0; i < 4; i++) {
                int idx4 = tid + i * 256;        // f32x4 index, 1024 total
                int q = idx4 >> 4;
                float L = 0.f;
                for (int cc = 0; cc < nch; cc++) L += Lp[cc * 64 + q];
                f32x4 v = *(f32x4*)&Out[gbase + idx4 * 4];
                for (int cc = 1; cc < nch; cc++) {
                    const unsigned short* pp =
                        &Part[(((size_t)b * 64 + qt) * 3 + (cc - 1)) * 4096 + idx4 * 4];
                    v[0] += b2f(pp[0]); v[1] += b2f(pp[1]);
                    v[2] += b2f(pp[2]); v[3] += b2f(pp[3]);
                }
                float inv = 1.0f / L;
                v[0] *= inv; v[1] *= inv; v[2] *= inv; v[3] *= inv;
                *(f32x4*)&Out[gbase + idx4 * 4] = v;
            }
        }
    }
}

extern "C" void kernel_launch(void* const* d_in, const int* in_sizes, int n_in,
                              void* d_out, int out_size, void* d_ws, size_t ws_size,
                              hipStream_t stream) {
    const float* X  = (const float*)d_in[0];
    const float* Wq = (const float*)d_in[1];
    const float* Wk = (const float*)d_in[2];
    const float* Wv = (const float*)d_in[3];
    float* out = (float*)d_out;

    char* ws = (char*)d_ws;
    size_t szQ = (size_t)Bn * Tn * Hn * sizeof(unsigned short);  // 4 MiB
    unsigned short* Qp  = (unsigned short*)(ws);
    unsigned short* Kp  = (unsigned short*)(ws + szQ);
    unsigned short* VTp = (unsigned short*)(ws + 2 * szQ);
    unsigned short* WT  = (unsigned short*)(ws + 3 * szQ);                      // 48 KiB
    int*            Ct  = (int*)(ws + 3 * szQ + (64 << 10));                    // 2 KiB
    float*          Lp  = (float*)(ws + 3 * szQ + (80 << 10));                  // 512 KiB
    unsigned short* Pt  = (unsigned short*)(ws + 3 * szQ + (80 << 10) + (512 << 10)); // 12 MiB

    wtrans<<<3, 256, 0, stream>>>(Wq, Wk, Wv, WT, Ct);
    qkv<<<Bn * Tn / 64, 256, 0, stream>>>(X, WT, Qp, Kp, VTp);
    attn<<<1280, 256, 0, stream>>>(Qp, Kp, VTp, out, Pt, Lp, Ct);
}

// Round 11
// 128.999 us; speedup vs baseline: 2.2889x; 2.2889x over previous
//
#include <hip/hip_runtime.h>
#include <hip/hip_bf16.h>

// Causal attention head. B=8, T=4096, D_EMBED=128, HEAD=64. f32 wire, bf16 MFMA.
// Two dispatches: qkv (with inlined W-transpose + zero-init) and attn (balanced
// split-k, LLC-atomic accumulation, last-block normalize; no cache-flush ops).
typedef __attribute__((ext_vector_type(8))) short bf16x8;
typedef __attribute__((ext_vector_type(4))) short short4v;
typedef __attribute__((ext_vector_type(4))) float f32x4;

#define MFMA16(a, b, c) __builtin_amdgcn_mfma_f32_16x16x32_bf16((a), (b), (c), 0, 0, 0)

// K=16 MFMA: P's S^T C-layout == its A-frag layout -> PV straight from registers.
// (correctness-verified on gfx950 in round 9: absmax 0.015625)
#if __has_builtin(__builtin_amdgcn_mfma_f32_16x16x16bf16_1k)
#define HAVE_X16 1
#define MFMAX16(a, b, c) __builtin_amdgcn_mfma_f32_16x16x16bf16_1k((a), (b), (c), 0, 0, 0)
#elif __has_builtin(__builtin_amdgcn_mfma_f32_16x16x16_bf16)
#define HAVE_X16 1
#define MFMAX16(a, b, c) __builtin_amdgcn_mfma_f32_16x16x16_bf16((a), (b), (c), 0, 0, 0)
#else
#define HAVE_X16 0
#endif

constexpr int Bn = 8, Tn = 4096, Dn = 128, Hn = 64;

__device__ inline unsigned short f2b(float f) {
    union { float f; unsigned u; } v; v.f = f;
    unsigned r = v.u + 0x7fff + ((v.u >> 16) & 1);   // RNE, inputs finite
    return (unsigned short)(r >> 16);
}
#if __has_builtin(__builtin_amdgcn_cvt_pk_bf16_f32)
typedef __attribute__((ext_vector_type(2))) __bf16 bf16x2_t;
__device__ inline unsigned pk2(float a, float b) {
    union { bf16x2_t v; unsigned u; } c;
    c.v = __builtin_amdgcn_cvt_pk_bf16_f32(a, b);
    return c.u;
}
#else
__device__ inline unsigned pk2(float a, float b) {
    return (unsigned)f2b(a) | ((unsigned)f2b(b) << 16);
}
#endif
__device__ inline short4v pk4(float a, float b, float c, float d) {
    union { unsigned u[2]; short4v s; } r;
    r.u[0] = pk2(a, b); r.u[1] = pk2(c, d);
    return r.s;
}

// ---- Kernel 1: QKV projection with inlined W transpose + zero-init of
// Out / Lsum / cnt (replaces wtrans kernel and all memset nodes). ----
__global__ __launch_bounds__(256) void qkv(const float* __restrict__ X,
                                           const float* __restrict__ Wq,
                                           const float* __restrict__ Wk,
                                           const float* __restrict__ Wv,
                                           unsigned short* __restrict__ Qp,
                                           unsigned short* __restrict__ Kp,
                                           unsigned short* __restrict__ VTp,
                                           float* __restrict__ Out,
                                           float* __restrict__ Lsum,
                                           int* __restrict__ cnt) {
    __shared__ unsigned short xt[64 * 136];   // X tile bf16
    __shared__ unsigned short wt[64 * 136];   // W^T tile bf16 (one mat at a time)
    __shared__ unsigned short ot[64 * 72];    // output staging
    int tid = threadIdx.x, w = tid >> 6, lane = tid & 63, quad = lane >> 4, l15 = lane & 15;
    int g = blockIdx.x;
    int m0 = g * 64;
    int b = m0 >> 12, tloc = m0 & (Tn - 1);
    const float kLog2Scale = 0.12751879523175464f;  // (1/sqrt(128)) * log2(e)

    // zero-init: Out (this block's 4096 f32), Lsum slice, counters
    #pragma unroll
    for (int i = 0; i < 4; i++)
        *(f32x4*)&Out[(size_t)g * 4096 + (size_t)(tid + i * 256) * 4] = (f32x4){0.f, 0.f, 0.f, 0.f};
    if (tid < 64) Lsum[g * 64 + tid] = 0.f;
    if (g == 0) { cnt[tid] = 0; cnt[tid + 256] = 0; }

    // stage X tile (coalesced f32x4 -> bf16)
    #pragma unroll
    for (int c = 0; c < 8; c++) {
        int e = tid * 4 + c * 1024;
        int row = e >> 7, col = e & 127;
        f32x4 v = *(const f32x4*)&X[(size_t)(m0 + row) * Dn + col];
        *(short4v*)&xt[row * 136 + col] = pk4(v[0], v[1], v[2], v[3]);
    }
    __syncthreads();

    bf16x8 a[4];
    #pragma unroll
    for (int kt = 0; kt < 4; kt++)
        a[kt] = *(const bf16x8*)&xt[(w * 16 + l15) * 136 + kt * 32 + quad * 8];

    for (int mat = 0; mat < 3; mat++) {
        const float* W = (mat == 0) ? Wq : (mat == 1) ? Wk : Wv;
        __syncthreads();   // prior mat's wt frag reads + ot copy-out done
        // transpose W[k][n] f32 -> wt[n][k] bf16 (coalesced reads)
        #pragma unroll
        for (int ps = 0; ps < 8; ps++) {
            int k = (tid >> 4) + ps * 16;
            int n4 = (tid & 15) * 4;
            f32x4 wv = *(const f32x4*)&W[k * Hn + n4];
            wt[(n4 + 0) * 136 + k] = f2b(wv[0]);
            wt[(n4 + 1) * 136 + k] = f2b(wv[1]);
            wt[(n4 + 2) * 136 + k] = f2b(wv[2]);
            wt[(n4 + 3) * 136 + k] = f2b(wv[3]);
        }
        __syncthreads();

        f32x4 acc[4];
        #pragma unroll
        for (int nt = 0; nt < 4; nt++) {
            acc[nt] = (f32x4){0.f, 0.f, 0.f, 0.f};
            const unsigned short* wtm = &wt[(nt * 16 + l15) * 136 + quad * 8];
            #pragma unroll
            for (int kt = 0; kt < 4; kt++)
                acc[nt] = MFMA16(a[kt], *(const bf16x8*)&wtm[kt * 32], acc[nt]);
        }
        __syncthreads();
        if (mat < 2) {
            float sc = (mat == 0) ? kLog2Scale : 1.0f;   // fold softmax scale into Q
            #pragma unroll
            for (int nt = 0; nt < 4; nt++)
                #pragma unroll
                for (int rg = 0; rg < 4; rg++)
                    ot[(w * 16 + quad * 4 + rg) * 72 + nt * 16 + l15] = f2b(acc[nt][rg] * sc);
        } else {
            #pragma unroll
            for (int nt = 0; nt < 4; nt++)
                *(short4v*)&ot[(nt * 16 + l15) * 72 + w * 16 + quad * 4] =
                    pk4(acc[nt][0], acc[nt][1], acc[nt][2], acc[nt][3]);
        }
        __syncthreads();
        if (mat < 2) {
            unsigned short* O = mat ? Kp : Qp;
            #pragma unroll
            for (int i = 0; i < 2; i++) {
                int row = (tid >> 3) + 32 * i, ch8 = tid & 7;
                *(bf16x8*)&O[(size_t)(m0 + row) * Hn + ch8 * 8] = *(const bf16x8*)&ot[row * 72 + ch8 * 8];
            }
        } else {
            #pragma unroll
            for (int i = 0; i < 2; i++) {
                int h = (tid >> 3) + 32 * i, ch8 = tid & 7;
                *(bf16x8*)&VTp[((size_t)(b * Hn + h)) * Tn + tloc + ch8 * 8] = *(const bf16x8*)&ot[h * 72 + ch8 * 8];
            }
        }
    }
}

// ---- Kernel 2: balanced split-k flash attention. Partials accumulate into the
// zeroed Out via relaxed device-scope atomicAdd (LLC-coherent, no cache flushes);
// per-(b,qt) counter + last-block normalize. ----
__global__ __launch_bounds__(256) void attn(const unsigned short* __restrict__ Qp,
                                            const unsigned short* __restrict__ Kp,
                                            const unsigned short* __restrict__ VTp,
                                            float* __restrict__ Out,
                                            float* __restrict__ Lsum,
                                            int* __restrict__ cnt) {
    __shared__ __align__(16) char shmem[18432];      // Ks+Vs, reused as Cbuf in epilogue
    unsigned short* Ks = (unsigned short*)shmem;     // [64][72]
    unsigned short* Vs = Ks + 64 * 72;               // [64][72]
#if !HAVE_X16
    __shared__ __align__(16) unsigned short Ps[4][32 * 40];
#endif
    __shared__ float Lbuf[2][64];
    __shared__ int lastflag;

    int idx = blockIdx.x;
    int b = idx & 7;
    int c = 159 - (idx >> 3);                        // big chunks dispatch first
    int qt, ch, nch;
    if (c < 16)      { qt = c;                 ch = 0;          nch = 1; }
    else if (c < 48) { int t = c - 16; qt = 16 + (t >> 1); ch = t & 1;      nch = 2; }
    else if (c < 96) { int t = c - 48; int q3 = t / 3; qt = 32 + q3; ch = t - 3 * q3; nch = 3; }
    else             { int t = c - 96; qt = 48 + (t >> 2); ch = t & 3;      nch = 4; }
    int k0 = ch * 16, k1 = min(qt, k0 + 15);

    int tid = threadIdx.x, w = tid >> 6, lane = tid & 63, quad = lane >> 4, l15 = lane & 15;
    int qh = w & 1, kh = w >> 1;
    int Q0 = qt * 64;
    const unsigned short* Kb = Kp + (size_t)b * Tn * Hn;
    const unsigned short* Vb = VTp + (size_t)b * Hn * Tn;

    int srow = tid >> 3, scol = (tid & 7) * 8;       // staging: 2 f32x4/thread/tile
    const f32x4* Ksrc = (const f32x4*)Kb;

    f32x4 kr[2], vr[2];
    #pragma unroll
    for (int i = 0; i < 2; i++) kr[i] = Ksrc[k0 * 512 + tid + i * 256];
    #pragma unroll
    for (int i = 0; i < 2; i++) vr[i] = *(const f32x4*)&Vb[(size_t)(srow + i * 32) * Tn + k0 * 64 + scol];

    bf16x8 qf[2][2];
    {
        const unsigned short* Qb = Qp + ((size_t)b * Tn + Q0 + qh * 32) * Hn;
        #pragma unroll
        for (int nq = 0; nq < 2; nq++)
            #pragma unroll
            for (int hc = 0; hc < 2; hc++)
                qf[nq][hc] = *(const bf16x8*)&Qb[(nq * 16 + l15) * Hn + hc * 32 + quad * 8];
    }

    f32x4 o[2][4];
    #pragma unroll
    for (int nq = 0; nq < 2; nq++)
        #pragma unroll
        for (int nh = 0; nh < 4; nh++) o[nq][nh] = (f32x4){0.f, 0.f, 0.f, 0.f};
    float li[2] = {0.f, 0.f};

    for (int kt = k0; kt <= k1; kt++) {
        __syncthreads();
        #pragma unroll
        for (int i = 0; i < 2; i++) *(f32x4*)&Ks[(srow + i * 32) * 72 + scol] = kr[i];
        #pragma unroll
        for (int i = 0; i < 2; i++) *(f32x4*)&Vs[(srow + i * 32) * 72 + scol] = vr[i];
        __syncthreads();
        if (kt < k1) {   // prefetch next tile; latency overlaps compute
            #pragma unroll
            for (int i = 0; i < 2; i++) kr[i] = Ksrc[(kt + 1) * 512 + tid + i * 256];
            #pragma unroll
            for (int i = 0; i < 2; i++)
                vr[i] = *(const f32x4*)&Vb[(size_t)(srow + i * 32) * Tn + (kt + 1) * 64 + scol];
        }

        bf16x8 kf[2][2];
        #pragma unroll
        for (int mt = 0; mt < 2; mt++)
            #pragma unroll
            for (int hc = 0; hc < 2; hc++)
                kf[mt][hc] = *(const bf16x8*)&Ks[(kh * 32 + mt * 16 + l15) * 72 + hc * 32 + quad * 8];

        // S^T tiles: rows k' = mt*16+quad*4+rg, cols q = nq*16+l15 (log2-scaled)
        f32x4 s[2][2];
        #pragma unroll
        for (int mt = 0; mt < 2; mt++)
            #pragma unroll
            for (int nq = 0; nq < 2; nq++) {
                f32x4 acc = {0.f, 0.f, 0.f, 0.f};
                acc = MFMA16(kf[mt][0], qf[nq][0], acc);
                acc = MFMA16(kf[mt][1], qf[nq][1], acc);
                s[mt][nq] = acc;
            }

        bool diag = (kt == qt);
        int kbase = kt * 64 + kh * 32 + quad * 4;
        int qbase = Q0 + qh * 32 + l15;

#if HAVE_X16
        short4v vB[2][4];
        #pragma unroll
        for (int mt = 0; mt < 2; mt++)
            #pragma unroll
            for (int nh = 0; nh < 4; nh++)
                vB[mt][nh] = *(const short4v*)&Vs[(nh * 16 + l15) * 72 + kh * 32 + mt * 16 + quad * 4];
        short4v pkv[2][2];
        #pragma unroll
        for (int mt = 0; mt < 2; mt++) {
            #pragma unroll
            for (int nq = 0; nq < 2; nq++) {
                float p[4];
                #pragma unroll
                for (int rg = 0; rg < 4; rg++) {
                    float pe = __builtin_amdgcn_exp2f(s[mt][nq][rg]);
                    if (diag && (kbase + mt * 16 + rg > qbase + nq * 16)) pe = 0.f;
                    li[nq] += pe;
                    p[rg] = pe;
                }
                pkv[mt][nq] = pk4(p[0], p[1], p[2], p[3]);
            }
        }
        #pragma unroll
        for (int mt = 0; mt < 2; mt++)
            #pragma unroll
            for (int nq = 0; nq < 2; nq++)
                #pragma unroll
                for (int nh = 0; nh < 4; nh++)
                    o[nq][nh] = MFMAX16(pkv[mt][nq], vB[mt][nh], o[nq][nh]);
#else
        bf16x8 vf[4];
        #pragma unroll
        for (int nh = 0; nh < 4; nh++)
            vf[nh] = *(const bf16x8*)&Vs[(nh * 16 + l15) * 72 + kh * 32 + quad * 8];
        unsigned short* Pw = &Ps[w][0];
        #pragma unroll
        for (int mt = 0; mt < 2; mt++) {
            #pragma unroll
            for (int nq = 0; nq < 2; nq++) {
                float p[4];
                #pragma unroll
                for (int rg = 0; rg < 4; rg++) {
                    float pe = __builtin_amdgcn_exp2f(s[mt][nq][rg]);
                    if (diag && (kbase + mt * 16 + rg > qbase + nq * 16)) pe = 0.f;
                    li[nq] += pe;
                    p[rg] = pe;
                }
                *(short4v*)&Pw[(nq * 16 + l15) * 40 + mt * 16 + quad * 4] = pk4(p[0], p[1], p[2], p[3]);
            }
        }
        bf16x8 pf[2];
        #pragma unroll
        for (int nq = 0; nq < 2; nq++)
            pf[nq] = *(const bf16x8*)&Pw[(nq * 16 + l15) * 40 + quad * 8];
        #pragma unroll
        for (int nq = 0; nq < 2; nq++)
            #pragma unroll
            for (int nh = 0; nh < 4; nh++)
                o[nq][nh] = MFMA16(pf[nq], vf[nh], o[nq][nh]);
#endif
    }

    // ---- epilogue: combine kh halves in LDS ----
    __syncthreads();                                  // loop LDS reads done; reuse shmem
    float (*Cbuf)[32][66] = (float (*)[32][66])shmem; // [2][32][66] = 16896 B
    #pragma unroll
    for (int nq = 0; nq < 2; nq++) {
        li[nq] += __shfl_xor(li[nq], 16);
        li[nq] += __shfl_xor(li[nq], 32);
    }
    if (lane < 16) {
        Lbuf[kh][qh * 32 + lane]      = li[0];
        Lbuf[kh][qh * 32 + 16 + lane] = li[1];
    }
    if (kh == 1) {
        #pragma unroll
        for (int nq = 0; nq < 2; nq++)
            #pragma unroll
            for (int nh = 0; nh < 4; nh++)
                #pragma unroll
                for (int rg = 0; rg < 4; rg++)
                    Cbuf[qh][nq * 16 + quad * 4 + rg][nh * 16 + l15] = o[nq][nh][rg];
    }
    __syncthreads();

    if (nch == 1) {
        if (kh == 0) {
            #pragma unroll
            for (int nq = 0; nq < 2; nq++) {
                #pragma unroll
                for (int rg = 0; rg < 4; rg++) {
                    int qloc = nq * 16 + quad * 4 + rg;
                    float inv = 1.0f / (Lbuf[0][qh * 32 + qloc] + Lbuf[1][qh * 32 + qloc]);
                    size_t row = (size_t)b * Tn + Q0 + qh * 32 + qloc;
                    #pragma unroll
                    for (int nh = 0; nh < 4; nh++)
                        Out[row * Hn + nh * 16 + l15] =
                            (o[nq][nh][rg] + Cbuf[qh][qloc][nh * 16 + l15]) * inv;
                }
            }
        }
    } else {
        // accumulate unnormalized partials at LLC (relaxed device-scope atomics)
        if (kh == 0) {
            #pragma unroll
            for (int nq = 0; nq < 2; nq++) {
                #pragma unroll
                for (int rg = 0; rg < 4; rg++) {
                    int qloc = nq * 16 + quad * 4 + rg;
                    size_t row = (size_t)b * Tn + Q0 + qh * 32 + qloc;
                    #pragma unroll
                    for (int nh = 0; nh < 4; nh++)
                        atomicAdd(&Out[row * Hn + nh * 16 + l15],
                                  o[nq][nh][rg] + Cbuf[qh][qloc][nh * 16 + l15]);
                }
            }
        }
        if (tid < 64)
            atomicAdd(&Lsum[(b << 12) + Q0 + tid], Lbuf[0][tid] + Lbuf[1][tid]);
        __threadfence_block();   // s_waitcnt only: this block's atomics executed at LLC
        __syncthreads();
        if (tid == 0)
            lastflag = (atomicAdd(&cnt[b * 64 + qt], 1) == nch - 1);
        __syncthreads();
        if (lastflag) {          // all chunks' atomics are in LLC; lines never plain-read before
            __threadfence_block();
            size_t gbase = ((size_t)b * Tn + Q0) * Hn;
            #pragma unroll
            for (int i = 0; i < 4; i++) {
                int idx4 = tid + i * 256;            // 1024 f32x4 = 64 q x 64 h
                int q = idx4 >> 4;
                float inv = 1.0f / Lsum[(b << 12) + Q0 + q];
                f32x4 v = *(f32x4*)&Out[gbase + (size_t)idx4 * 4];
                v[0] *= inv; v[1] *= inv; v[2] *= inv; v[3] *= inv;
                *(f32x4*)&Out[gbase + (size_t)idx4 * 4] = v;
            }
        }
    }
}

extern "C" void kernel_launch(void* const* d_in, const int* in_sizes, int n_in,
                              void* d_out, int out_size, void* d_ws, size_t ws_size,
                              hipStream_t stream) {
    const float* X  = (const float*)d_in[0];
    const float* Wq = (const float*)d_in[1];
    const float* Wk = (const float*)d_in[2];
    const float* Wv = (const float*)d_in[3];
    float* out = (float*)d_out;

    char* ws = (char*)d_ws;
    size_t szQ = (size_t)Bn * Tn * Hn * sizeof(unsigned short);  // 4 MiB
    unsigned short* Qp  = (unsigned short*)(ws);
    unsigned short* Kp  = (unsigned short*)(ws + szQ);
    unsigned short* VTp = (unsigned short*)(ws + 2 * szQ);
    float*          Ls  = (float*)(ws + 3 * szQ);                // 128 KiB (8*4096 f32)
    int*            Ct  = (int*)(ws + 3 * szQ + (128 << 10));    // 2 KiB

    qkv<<<Bn * Tn / 64, 256, 0, stream>>>(X, Wq, Wk, Wv, Qp, Kp, VTp, out, Ls, Ct);
    attn<<<1280, 256, 0, stream>>>(Qp, Kp, VTp, out, Ls, Ct);
}